// Round 9
// baseline (239.779 us; speedup 1.0000x reference)
//
#include <hip/hip_runtime.h>

// out[r][c] = x[r][c] * diag[c]
// x: 16384 x 2048 fp32, diag: 2048 fp32. Memory-bound broadcast multiply.
//
// v9: chip-wide PHASE SEPARATION, two dispatches on the same stream.
// Ledger so far: 9 single-pass variants = 71-92 us, all with in-window
// HBM traffic pinned at 201 MB (FETCH=65.6=half of x, WRITE=134) and
// ~2.8 TB/s, while the harness's pure-write fill does 6.7 TB/s in the
// same environment. Every cache hint (nt load/store/both) left FETCH
// unchanged -> nt doesn't steer MALL allocation. Per-thread MLP ruled
// out (v4-v6 + Little's law). Remaining difference vs the fill: our
// window mixes read+write; the fill's is pure write.
//  - Pass 1 (warm): pure-read sweep of x, normal loads (allocate in L3),
//    value sunk with asm volatile (rule #17: keep the load live).
//    Pure read window + installs ALL of x (134 MB < 256 MB L3).
//  - Pass 2 (main): x reads ~all L3-hit; out via nt store (straight to
//    HBM, no allocation -> x stays resident for the next iteration).
//    HBM window is ~pure write, fill-shaped.
// Mechanism check: warm row FETCH~65MB/WRITE~0; main row FETCH<<65MB,
// WRITE~134MB. Success: combined < 60 us, headline ~<205. If main stays
// ~70 us despite warm L3: phase theory falsified -> revert v7, declare
// roofline.
using f4 = __attribute__((ext_vector_type(4))) float;

__global__ __launch_bounds__(256) void warm_x_kernel(
    const f4* __restrict__ x, int n4) {
    int i = blockIdx.x * blockDim.x + threadIdx.x;
    if (i < n4) {
        f4 v = x[i];                     // normal load: allocate in L2/L3
        asm volatile("" :: "v"(v));      // liveness sink, no DCE
    }
}

__global__ __launch_bounds__(256) void DiagonalDense_kernel(
    const f4* __restrict__ x,
    const f4* __restrict__ diag,
    f4* __restrict__ out,
    int n4) {
    int i = blockIdx.x * blockDim.x + threadIdx.x;
    if (i < n4) {
        f4 xv = x[i];                    // ~all L3 hits after warm pass
        f4 dv = diag[i & 511];           // L1-resident broadcast
        __builtin_nontemporal_store(xv * dv, &out[i]);  // no L3 alloc:
                                         // don't evict x, stream to HBM
    }
}

extern "C" void kernel_launch(void* const* d_in, const int* in_sizes, int n_in,
                              void* d_out, int out_size, void* d_ws, size_t ws_size,
                              hipStream_t stream) {
    const f4* x    = (const f4*)d_in[0];   // 16384*2048 fp32
    const f4* diag = (const f4*)d_in[1];   // 2048 fp32
    f4* out        = (f4*)d_out;

    const int n  = out_size;       // 33,554,432 floats
    const int n4 = n / 4;          // 8,388,608 float4s (exactly divisible)
    const int block = 256;
    const int grid  = (n4 + block - 1) / block;   // 32768 blocks, exact

    warm_x_kernel<<<grid, block, 0, stream>>>(x, n4);
    DiagonalDense_kernel<<<grid, block, 0, stream>>>(x, diag, out, n4);
}